// Round 8
// baseline (170.971 us; speedup 1.0000x reference)
//
#include <hip/hip_runtime.h>
#include <hip/hip_bf16.h>
#include <hip/hip_fp16.h>

// Problem constants
#define BB 2
#define SS 2048
#define DD 1024
#define HH 16
#define HD 64
#define MM (BB * SS)   // 4096

typedef __attribute__((ext_vector_type(8))) _Float16 half8;
typedef __attribute__((ext_vector_type(4))) float f32x4;
typedef __attribute__((ext_vector_type(4))) short short4v;

static __device__ __forceinline__ short f2h(float f) {
    _Float16 h = (_Float16)f;
    return __builtin_bit_cast(short, h);
}

static __device__ __forceinline__ unsigned pk2(float a, float b) {
    auto h = __builtin_amdgcn_cvt_pkrtz(a, b);
    return __builtin_bit_cast(unsigned, h);
}

static __device__ __forceinline__ void gload16(const void* g, void* l) {
    __builtin_amdgcn_global_load_lds(
        (const __attribute__((address_space(1))) unsigned*)g,
        (__attribute__((address_space(3))) unsigned*)l, 16, 0, 0);
}

// ---------------------------------------------------------------------------
// fp32 -> fp16 conversion (activations+weights) + mask -> f32 bias array.
// ---------------------------------------------------------------------------
__global__ __launch_bounds__(256) void cvt_kernel(
    const float* __restrict__ q, const float* __restrict__ k, const float* __restrict__ v,
    const float* __restrict__ wq, const float* __restrict__ wk,
    const float* __restrict__ wv, const float* __restrict__ wo,
    const int* __restrict__ mask,
    short* __restrict__ q16, short* __restrict__ k16, short* __restrict__ v16,
    short* __restrict__ wq16, short* __restrict__ wk16,
    short* __restrict__ wv16, short* __restrict__ wo16,
    float* __restrict__ mbias)
{
    const int i = (blockIdx.x * 256 + threadIdx.x) * 4;
    if (blockIdx.y == 7) {
        if (i >= BB * SS) return;
        const int4 mi = *(const int4*)&mask[i];
        float4 f;
        f.x = (mi.x == 0) ? -1.0e9f : 0.0f;
        f.y = (mi.y == 0) ? -1.0e9f : 0.0f;
        f.z = (mi.z == 0) ? -1.0e9f : 0.0f;
        f.w = (mi.w == 0) ? -1.0e9f : 0.0f;
        *(float4*)&mbias[i] = f;
        return;
    }
    const float* src; short* dst; int n;
    switch (blockIdx.y) {
        case 0: src = q;  dst = q16;  n = MM * DD; break;
        case 1: src = k;  dst = k16;  n = MM * DD; break;
        case 2: src = v;  dst = v16;  n = MM * DD; break;
        case 3: src = wq; dst = wq16; n = DD * DD; break;
        case 4: src = wk; dst = wk16; n = DD * DD; break;
        case 5: src = wv; dst = wv16; n = DD * DD; break;
        default: src = wo; dst = wo16; n = DD * DD; break;
    }
    if (i >= n) return;
    const float4 f = *(const float4*)&src[i];
    short4v h;
    h.x = f2h(f.x); h.y = f2h(f.y); h.z = f2h(f.z); h.w = f2h(f.w);
    *(short4v*)&dst[i] = h;
}

// ---------------------------------------------------------------------------
// fp16 MFMA GEMM: C = A @ W^T + bias.  128x128 tile, BK=64, 4 waves,
// 16x16x32 MFMA, global_load_lds w=16 + XOR-swizzled ds_read_b128.
// ---------------------------------------------------------------------------
__global__ __launch_bounds__(256) void gemm_f16(
    const short* __restrict__ A0, const short* __restrict__ A1, const short* __restrict__ A2,
    const short* __restrict__ W0, const short* __restrict__ W1, const short* __restrict__ W2,
    const float* __restrict__ b0, const float* __restrict__ b1, const float* __restrict__ b2,
    void* __restrict__ C0, void* __restrict__ C1, void* __restrict__ C2,
    int mode0, int mode1, int mode2)
{
    const int z = blockIdx.z;
    const short* A = (z == 0) ? A0 : (z == 1) ? A1 : A2;
    const short* W = (z == 0) ? W0 : (z == 1) ? W1 : W2;
    const float* bias = (z == 0) ? b0 : (z == 1) ? b1 : b2;
    void* C = (z == 0) ? C0 : (z == 1) ? C1 : C2;
    const int mode = (z == 0) ? mode0 : (z == 1) ? mode1 : mode2;

    __shared__ short Asw[128 * 64];
    __shared__ short Bsw[128 * 64];

    const int t = threadIdx.x;
    const int wave = t >> 6, lane = t & 63;
    const int lr = lane & 15, lq = lane >> 4;
    const int wr = wave >> 1, wc = wave & 1;
    const int m0 = blockIdx.x * 128, n0 = blockIdx.y * 128;
    const int K = DD;

    f32x4 acc[4][4] = {};

    for (int k0 = 0; k0 < K; k0 += 64) {
        #pragma unroll
        for (int c = 0; c < 4; ++c) {
            const int b = c * 4096 + t * 16;
            const int row = b >> 7;
            const int coff = b & 127;
            const int scoff = coff ^ ((row & 7) << 4);
            gload16((const char*)A + ((size_t)(m0 + row) * K + k0) * 2 + scoff,
                    (char*)Asw + b);
            gload16((const char*)W + ((size_t)(n0 + row) * K + k0) * 2 + scoff,
                    (char*)Bsw + b);
        }
        __syncthreads();

        half8 af[4][2], bf[4][2];
        #pragma unroll
        for (int mi = 0; mi < 4; ++mi) {
            const int row = wr * 64 + mi * 16 + lr;
            #pragma unroll
            for (int ks = 0; ks < 2; ++ks) {
                const int col = (ks * 32 + lq * 8) ^ ((row & 7) << 3);
                af[mi][ks] = *(const half8*)&Asw[row * 64 + col];
            }
        }
        #pragma unroll
        for (int ni = 0; ni < 4; ++ni) {
            const int row = wc * 64 + ni * 16 + lr;
            #pragma unroll
            for (int ks = 0; ks < 2; ++ks) {
                const int col = (ks * 32 + lq * 8) ^ ((row & 7) << 3);
                bf[ni][ks] = *(const half8*)&Bsw[row * 64 + col];
            }
        }
        #pragma unroll
        for (int ks = 0; ks < 2; ++ks)
            #pragma unroll
            for (int mi = 0; mi < 4; ++mi)
                #pragma unroll
                for (int ni = 0; ni < 4; ++ni)
                    acc[mi][ni] = __builtin_amdgcn_mfma_f32_16x16x32_f16(
                        af[mi][ks], bf[ni][ks], acc[mi][ni], 0, 0, 0);
        __syncthreads();
    }

    #pragma unroll
    for (int mi = 0; mi < 4; ++mi) {
        #pragma unroll
        for (int r = 0; r < 4; ++r) {
            const int m = m0 + wr * 64 + mi * 16 + lq * 4 + r;
            const int bidx = m >> 11;
            const int s = m & (SS - 1);
            #pragma unroll
            for (int ni = 0; ni < 4; ++ni) {
                const int n = n0 + wc * 64 + ni * 16 + lr;
                const float val = acc[mi][ni][r] + bias[n];
                if (mode == 0) {
                    ((float*)C)[(size_t)m * DD + n] = val;
                } else {
                    const int h = n >> 6, d = n & (HD - 1);
                    if (mode == 1)
                        ((short*)C)[(((size_t)bidx * HH + h) * SS + s) * HD + d] = f2h(val);
                    else
                        ((short*)C)[(((size_t)bidx * HH + h) * HD + d) * SS + s] = f2h(val);
                }
            }
        }
    }
}

// ---------------------------------------------------------------------------
// MFMA flash attention (fp16), swapped-QK^T + static-max softmax +
// 2-phase double-buffered K/V pipeline (stage t+1 before computing t; one
// barrier per tile).  P overlays Q's LDS (Q is reg-resident after prologue).
// Mask bias comes from a precomputed global f32 array (broadcast loads).
// LDS = 8K (Q/P) + 16K (K dbuf) + 16K (V dbuf) = 40960 B -> 4 blocks/CU.
// ---------------------------------------------------------------------------
__global__ __launch_bounds__(256) void attn_mfma_kernel(
    const short* __restrict__ q,
    const short* __restrict__ k,
    const short* __restrict__ vt,
    const float* __restrict__ mbias,
    short* __restrict__ x)
{
    const int qt = blockIdx.x;   // 0..31
    const int h  = blockIdx.y;   // 0..15
    const int b  = blockIdx.z;   // 0..1
    const int t = threadIdx.x;
    const int wave = t >> 6, lane = t & 63;
    const int lr = lane & 15;
    const int lq = lane >> 4;

    __shared__ short QPs[64 * 64];        // Q tile, then per-wave P tiles
    __shared__ short KsD[2][64 * 64];
    __shared__ short VtsD[2][64 * 64];

    const size_t base  = ((size_t)(b * HH + h)) * SS * HD;
    const size_t basev = ((size_t)(b * HH + h)) * HD * SS;
    const char* kb = (const char*)(k + base);
    const char* vb = (const char*)(vt + basev);

    // Stage Q tile (64 x 64) + K/V tile 0 into buffer 0
    {
        const char* qb = (const char*)(q + base + (size_t)qt * 64 * HD);
        #pragma unroll
        for (int c = 0; c < 2; ++c) {
            const int off = c * 4096 + t * 16;
            const int row = off >> 7, coff = off & 127;
            const int sw = coff ^ ((row & 7) << 4);
            gload16(qb + row * 128 + sw, (char*)QPs + off);
            gload16(kb + (size_t)row * 128 + sw, (char*)KsD[0] + off);
            gload16(vb + (size_t)row * (SS * 2) + sw, (char*)VtsD[0] + off);
        }
    }
    __syncthreads();

    half8 qf[2];
    #pragma unroll
    for (int ks = 0; ks < 2; ++ks) {
        const int r = wave * 16 + lr;
        qf[ks] = *(const half8*)&QPs[r * 64 + ((ks * 32 + lq * 8) ^ ((r & 7) << 3))];
    }
    __syncthreads();   // all waves done reading Q before P overwrites it

    float l_run = 0.0f;
    f32x4 o[4] = {};
    const float SC2 = 0.18033688011112042f;   // 0.125 * log2(e)
    const float* mrow = &mbias[b * SS];

    int cur = 0;
    for (int kv0 = 0; kv0 < SS; kv0 += 64) {
        // Issue next tile's staging loads (latency hidden under compute)
        if (kv0 + 64 < SS) {
            #pragma unroll
            for (int c = 0; c < 2; ++c) {
                const int off = c * 4096 + t * 16;
                const int row = off >> 7, coff = off & 127;
                const int sw = coff ^ ((row & 7) << 4);
                gload16(kb + (size_t)(kv0 + 64 + row) * 128 + sw,
                        (char*)KsD[cur ^ 1] + off);
                gload16(vb + (size_t)row * (SS * 2) + (kv0 + 64) * 2 + sw,
                        (char*)VtsD[cur ^ 1] + off);
            }
        }

        // Mask bias for this tile (global, L1/L2 broadcast)
        float4 mb[4];
        #pragma unroll
        for (int kt = 0; kt < 4; ++kt)
            mb[kt] = *(const float4*)&mrow[kv0 + kt * 16 + lq * 4];

        // Swapped QK^T: sc[kt] row = k (lq*4+r), col = q (lr)
        const short* Ks = KsD[cur];
        f32x4 sc[4] = {};
        __builtin_amdgcn_s_setprio(1);
        #pragma unroll
        for (int kt = 0; kt < 4; ++kt) {
            const int kr = kt * 16 + lr;
            #pragma unroll
            for (int ks = 0; ks < 2; ++ks) {
                half8 kf = *(const half8*)&Ks[kr * 64 + ((ks * 32 + lq * 8) ^ ((kr & 7) << 3))];
                sc[kt] = __builtin_amdgcn_mfma_f32_16x16x32_f16(kf, qf[ks], sc[kt], 0, 0, 0);
            }
        }
        __builtin_amdgcn_s_setprio(0);

        // p = exp2(sc*SC2 + mb); row-sum; pack into P (static max)
        short* Pw = &QPs[wave * 1024];
        float rs = 0.0f;
        #pragma unroll
        for (int kt = 0; kt < 4; ++kt) {
            const float p0 = exp2f(fmaf(sc[kt][0], SC2, mb[kt].x));
            const float p1 = exp2f(fmaf(sc[kt][1], SC2, mb[kt].y));
            const float p2 = exp2f(fmaf(sc[kt][2], SC2, mb[kt].z));
            const float p3 = exp2f(fmaf(sc[kt][3], SC2, mb[kt].w));
            rs += (p0 + p1) + (p2 + p3);
            const int cb = kt * 16 + lq * 4;
            *(unsigned*)&Pw[lr * 64 + ((cb)     ^ ((lr & 7) << 3))] = pk2(p0, p1);
            *(unsigned*)&Pw[lr * 64 + ((cb + 2) ^ ((lr & 7) << 3))] = pk2(p2, p3);
        }
        rs += __shfl_xor(rs, 16);
        rs += __shfl_xor(rs, 32);
        l_run += rs;

        // PV: A = P[q][k] (per-wave LDS), B = V[k][d] via Vt[d][k]
        const short* Vts = VtsD[cur];
        half8 pf[2];
        #pragma unroll
        for (int ks = 0; ks < 2; ++ks)
            pf[ks] = *(const half8*)&Pw[lr * 64 + ((ks * 32 + lq * 8) ^ ((lr & 7) << 3))];
        __builtin_amdgcn_s_setprio(1);
        #pragma unroll
        for (int dt = 0; dt < 4; ++dt) {
            const int dr = dt * 16 + lr;
            #pragma unroll
            for (int ks = 0; ks < 2; ++ks) {
                half8 vf = *(const half8*)&Vts[dr * 64 + ((ks * 32 + lq * 8) ^ ((dr & 7) << 3))];
                o[dt] = __builtin_amdgcn_mfma_f32_16x16x32_f16(pf[ks], vf, o[dt], 0, 0, 0);
            }
        }
        __builtin_amdgcn_s_setprio(0);

        // Single barrier per tile: drains next-tile staging (vmcnt) and
        // guards buf reuse + per-wave P region timing.
        __syncthreads();
        cur ^= 1;
    }

    // Epilogue: normalize by 1/l (broadcast from lane q), write fp16 (B,S,D)
    const float li = 1.0f / l_run;
    float linv[4];
    #pragma unroll
    for (int r = 0; r < 4; ++r) linv[r] = __shfl(li, lq * 4 + r);
    const int srow = qt * 64 + wave * 16;
    #pragma unroll
    for (int dt = 0; dt < 4; ++dt)
        #pragma unroll
        for (int r = 0; r < 4; ++r)
            x[((size_t)b * SS + srow + lq * 4 + r) * DD + h * HD + dt * 16 + lr] =
                f2h(o[dt][r] * linv[r]);
}

extern "C" void kernel_launch(void* const* d_in, const int* in_sizes, int n_in,
                              void* d_out, int out_size, void* d_ws, size_t ws_size,
                              hipStream_t stream) {
    const float* query = (const float*)d_in[0];
    const float* key   = (const float*)d_in[1];
    const float* value = (const float*)d_in[2];
    const int*   mask  = (const int*)d_in[3];
    const float* Wq = (const float*)d_in[4];
    const float* bq = (const float*)d_in[5];
    const float* Wk = (const float*)d_in[6];
    const float* bk = (const float*)d_in[7];
    const float* Wv = (const float*)d_in[8];
    const float* bv = (const float*)d_in[9];
    const float* Wo = (const float*)d_in[10];
    const float* bo = (const float*)d_in[11];
    float* out = (float*)d_out;

    const size_t NACT = (size_t)MM * DD;   // 4M elements
    const size_t NW   = (size_t)DD * DD;   // 1M elements
    short* qry16 = (short*)d_ws;           // later reused as x16 (attn output)
    short* key16 = qry16 + NACT;
    short* val16 = key16 + NACT;
    short* wq16  = val16 + NACT;
    short* wk16  = wq16 + NW;
    short* wv16  = wk16 + NW;
    short* wo16  = wv16 + NW;
    short* q_ws  = wo16 + NW;
    short* k_ws  = q_ws + NACT;
    short* vt_ws = k_ws + NACT;
    float* mbias = (float*)(vt_ws + NACT);
    short* x16   = qry16;                  // reuse

    // 1. Convert activations + weights to fp16; build mask-bias array
    cvt_kernel<<<dim3(NACT / 4 / 256, 8), 256, 0, stream>>>(
        query, key, value, Wq, Wk, Wv, Wo, mask,
        qry16, key16, val16, wq16, wk16, wv16, wo16, mbias);

    // 2. Q/K/V projections (fused via grid.z)
    gemm_f16<<<dim3(MM / 128, DD / 128, 3), 256, 0, stream>>>(
        qry16, key16, val16, wq16, wk16, wv16, bq, bk, bv,
        q_ws, k_ws, vt_ws, 1, 1, 2);

    // 3. Attention (QBLK=64, 2-phase dbuf)
    attn_mfma_kernel<<<dim3(SS / 64, HH, BB), 256, 0, stream>>>(
        q_ws, k_ws, vt_ws, mbias, x16);

    // 4. Output projection
    gemm_f16<<<dim3(MM / 128, DD / 128, 1), 256, 0, stream>>>(
        x16, x16, x16, wo16, wo16, wo16, bo, bo, bo,
        out, out, out, 0, 0, 0);
}

// Round 10
// 168.101 us; speedup vs baseline: 1.0171x; 1.0171x over previous
//
#include <hip/hip_runtime.h>
#include <hip/hip_bf16.h>
#include <hip/hip_fp16.h>

// Problem constants
#define BB 2
#define SS 2048
#define DD 1024
#define HH 16
#define HD 64
#define MM (BB * SS)   // 4096

typedef __attribute__((ext_vector_type(8))) _Float16 half8;
typedef __attribute__((ext_vector_type(4))) float f32x4;
typedef __attribute__((ext_vector_type(4))) short short4v;

static __device__ __forceinline__ short f2h(float f) {
    _Float16 h = (_Float16)f;
    return __builtin_bit_cast(short, h);
}

static __device__ __forceinline__ unsigned pk2(float a, float b) {
    auto h = __builtin_amdgcn_cvt_pkrtz(a, b);
    return __builtin_bit_cast(unsigned, h);
}

static __device__ __forceinline__ void gload16(const void* g, void* l) {
    __builtin_amdgcn_global_load_lds(
        (const __attribute__((address_space(1))) unsigned*)g,
        (__attribute__((address_space(3))) unsigned*)l, 16, 0, 0);
}

// ---------------------------------------------------------------------------
// fp32 -> fp16 conversion (activations+weights) + mask -> f32 bias array.
// ---------------------------------------------------------------------------
__global__ __launch_bounds__(256) void cvt_kernel(
    const float* __restrict__ q, const float* __restrict__ k, const float* __restrict__ v,
    const float* __restrict__ wq, const float* __restrict__ wk,
    const float* __restrict__ wv, const float* __restrict__ wo,
    const int* __restrict__ mask,
    short* __restrict__ q16, short* __restrict__ k16, short* __restrict__ v16,
    short* __restrict__ wq16, short* __restrict__ wk16,
    short* __restrict__ wv16, short* __restrict__ wo16,
    float* __restrict__ mbias)
{
    const int i = (blockIdx.x * 256 + threadIdx.x) * 4;
    if (blockIdx.y == 7) {
        if (i >= BB * SS) return;
        const int4 mi = *(const int4*)&mask[i];
        float4 f;
        f.x = (mi.x == 0) ? -1.0e9f : 0.0f;
        f.y = (mi.y == 0) ? -1.0e9f : 0.0f;
        f.z = (mi.z == 0) ? -1.0e9f : 0.0f;
        f.w = (mi.w == 0) ? -1.0e9f : 0.0f;
        *(float4*)&mbias[i] = f;
        return;
    }
    const float* src; short* dst; int n;
    switch (blockIdx.y) {
        case 0: src = q;  dst = q16;  n = MM * DD; break;
        case 1: src = k;  dst = k16;  n = MM * DD; break;
        case 2: src = v;  dst = v16;  n = MM * DD; break;
        case 3: src = wq; dst = wq16; n = DD * DD; break;
        case 4: src = wk; dst = wk16; n = DD * DD; break;
        case 5: src = wv; dst = wv16; n = DD * DD; break;
        default: src = wo; dst = wo16; n = DD * DD; break;
    }
    if (i >= n) return;
    const float4 f = *(const float4*)&src[i];
    short4v h;
    h.x = f2h(f.x); h.y = f2h(f.y); h.z = f2h(f.z); h.w = f2h(f.w);
    *(short4v*)&dst[i] = h;
}

// ---------------------------------------------------------------------------
// fp16 MFMA GEMM: C = A @ W^T + bias.  128x128 tile, BK=64, 4 waves,
// 16x16x32 MFMA, global_load_lds w=16 + XOR-swizzled ds_read_b128.
// ---------------------------------------------------------------------------
__global__ __launch_bounds__(256) void gemm_f16(
    const short* __restrict__ A0, const short* __restrict__ A1, const short* __restrict__ A2,
    const short* __restrict__ W0, const short* __restrict__ W1, const short* __restrict__ W2,
    const float* __restrict__ b0, const float* __restrict__ b1, const float* __restrict__ b2,
    void* __restrict__ C0, void* __restrict__ C1, void* __restrict__ C2,
    int mode0, int mode1, int mode2)
{
    const int z = blockIdx.z;
    const short* A = (z == 0) ? A0 : (z == 1) ? A1 : A2;
    const short* W = (z == 0) ? W0 : (z == 1) ? W1 : W2;
    const float* bias = (z == 0) ? b0 : (z == 1) ? b1 : b2;
    void* C = (z == 0) ? C0 : (z == 1) ? C1 : C2;
    const int mode = (z == 0) ? mode0 : (z == 1) ? mode1 : mode2;

    __shared__ short Asw[128 * 64];
    __shared__ short Bsw[128 * 64];

    const int t = threadIdx.x;
    const int wave = t >> 6, lane = t & 63;
    const int lr = lane & 15, lq = lane >> 4;
    const int wr = wave >> 1, wc = wave & 1;
    const int m0 = blockIdx.x * 128, n0 = blockIdx.y * 128;
    const int K = DD;

    f32x4 acc[4][4] = {};

    for (int k0 = 0; k0 < K; k0 += 64) {
        #pragma unroll
        for (int c = 0; c < 4; ++c) {
            const int b = c * 4096 + t * 16;
            const int row = b >> 7;
            const int coff = b & 127;
            const int scoff = coff ^ ((row & 7) << 4);
            gload16((const char*)A + ((size_t)(m0 + row) * K + k0) * 2 + scoff,
                    (char*)Asw + b);
            gload16((const char*)W + ((size_t)(n0 + row) * K + k0) * 2 + scoff,
                    (char*)Bsw + b);
        }
        __syncthreads();

        half8 af[4][2], bf[4][2];
        #pragma unroll
        for (int mi = 0; mi < 4; ++mi) {
            const int row = wr * 64 + mi * 16 + lr;
            #pragma unroll
            for (int ks = 0; ks < 2; ++ks) {
                const int col = (ks * 32 + lq * 8) ^ ((row & 7) << 3);
                af[mi][ks] = *(const half8*)&Asw[row * 64 + col];
            }
        }
        #pragma unroll
        for (int ni = 0; ni < 4; ++ni) {
            const int row = wc * 64 + ni * 16 + lr;
            #pragma unroll
            for (int ks = 0; ks < 2; ++ks) {
                const int col = (ks * 32 + lq * 8) ^ ((row & 7) << 3);
                bf[ni][ks] = *(const half8*)&Bsw[row * 64 + col];
            }
        }
        #pragma unroll
        for (int ks = 0; ks < 2; ++ks)
            #pragma unroll
            for (int mi = 0; mi < 4; ++mi)
                #pragma unroll
                for (int ni = 0; ni < 4; ++ni)
                    acc[mi][ni] = __builtin_amdgcn_mfma_f32_16x16x32_f16(
                        af[mi][ks], bf[ni][ks], acc[mi][ni], 0, 0, 0);
        __syncthreads();
    }

    #pragma unroll
    for (int mi = 0; mi < 4; ++mi) {
        #pragma unroll
        for (int r = 0; r < 4; ++r) {
            const int m = m0 + wr * 64 + mi * 16 + lq * 4 + r;
            const int bidx = m >> 11;
            const int s = m & (SS - 1);
            #pragma unroll
            for (int ni = 0; ni < 4; ++ni) {
                const int n = n0 + wc * 64 + ni * 16 + lr;
                const float val = acc[mi][ni][r] + bias[n];
                if (mode == 0) {
                    ((float*)C)[(size_t)m * DD + n] = val;
                } else {
                    const int h = n >> 6, d = n & (HD - 1);
                    if (mode == 1)
                        ((short*)C)[(((size_t)bidx * HH + h) * SS + s) * HD + d] = f2h(val);
                    else
                        ((short*)C)[(((size_t)bidx * HH + h) * HD + d) * SS + s] = f2h(val);
                }
            }
        }
    }
}

// ---------------------------------------------------------------------------
// MFMA flash attention (fp16), swapped-QK^T + static-max softmax +
// 2-phase double-buffered K/V + MFMA row-sum (l = P @ ones via a constant
// ones B-fragment; lands in o's register layout, no shuffles) + b64 P-stores.
// LDS = 8K (Q/P overlay) + 16K (K dbuf) + 16K (V dbuf) = 40960 B.
// ---------------------------------------------------------------------------
__global__ __launch_bounds__(256) void attn_mfma_kernel(
    const short* __restrict__ q,
    const short* __restrict__ k,
    const short* __restrict__ vt,
    const float* __restrict__ mbias,
    short* __restrict__ x)
{
    const int qt = blockIdx.x;   // 0..31
    const int h  = blockIdx.y;   // 0..15
    const int b  = blockIdx.z;   // 0..1
    const int t = threadIdx.x;
    const int wave = t >> 6, lane = t & 63;
    const int lr = lane & 15;
    const int lq = lane >> 4;

    __shared__ short QPs[64 * 64];        // Q tile, then per-wave P tiles
    __shared__ short KsD[2][64 * 64];
    __shared__ short VtsD[2][64 * 64];

    const size_t base  = ((size_t)(b * HH + h)) * SS * HD;
    const size_t basev = ((size_t)(b * HH + h)) * HD * SS;
    const char* kb = (const char*)(k + base);
    const char* vb = (const char*)(vt + basev);

    // Stage Q tile (64 x 64) + K/V tile 0 into buffer 0
    {
        const char* qb = (const char*)(q + base + (size_t)qt * 64 * HD);
        #pragma unroll
        for (int c = 0; c < 2; ++c) {
            const int off = c * 4096 + t * 16;
            const int row = off >> 7, coff = off & 127;
            const int sw = coff ^ ((row & 7) << 4);
            gload16(qb + row * 128 + sw, (char*)QPs + off);
            gload16(kb + (size_t)row * 128 + sw, (char*)KsD[0] + off);
            gload16(vb + (size_t)row * (SS * 2) + sw, (char*)VtsD[0] + off);
        }
    }
    __syncthreads();

    half8 qf[2];
    #pragma unroll
    for (int ks = 0; ks < 2; ++ks) {
        const int r = wave * 16 + lr;
        qf[ks] = *(const half8*)&QPs[r * 64 + ((ks * 32 + lq * 8) ^ ((r & 7) << 3))];
    }
    __syncthreads();   // all waves done reading Q before P overwrites it

    f32x4 o[4] = {};
    f32x4 ol = {};                       // MFMA-accumulated row sums (l)
    const float SC2 = 0.18033688011112042f;   // 0.125 * log2(e)
    const float* mrow = &mbias[b * SS];

    const half8 ones8 = {1.0f16, 1.0f16, 1.0f16, 1.0f16,
                         1.0f16, 1.0f16, 1.0f16, 1.0f16};

    int cur = 0;
    for (int kv0 = 0; kv0 < SS; kv0 += 64) {
        // Issue next tile's staging loads (latency hidden under compute)
        if (kv0 + 64 < SS) {
            #pragma unroll
            for (int c = 0; c < 2; ++c) {
                const int off = c * 4096 + t * 16;
                const int row = off >> 7, coff = off & 127;
                const int sw = coff ^ ((row & 7) << 4);
                gload16(kb + (size_t)(kv0 + 64 + row) * 128 + sw,
                        (char*)KsD[cur ^ 1] + off);
                gload16(vb + (size_t)row * (SS * 2) + (kv0 + 64) * 2 + sw,
                        (char*)VtsD[cur ^ 1] + off);
            }
        }

        // Mask bias for this tile (global, L1/L2 broadcast)
        float4 mb[4];
        #pragma unroll
        for (int kt = 0; kt < 4; ++kt)
            mb[kt] = *(const float4*)&mrow[kv0 + kt * 16 + lq * 4];

        // Swapped QK^T: sc[kt] row = k (lq*4+r), col = q (lr)
        const short* Ks = KsD[cur];
        f32x4 sc[4] = {};
        __builtin_amdgcn_s_setprio(1);
        #pragma unroll
        for (int kt = 0; kt < 4; ++kt) {
            const int kr = kt * 16 + lr;
            #pragma unroll
            for (int ks = 0; ks < 2; ++ks) {
                half8 kf = *(const half8*)&Ks[kr * 64 + ((ks * 32 + lq * 8) ^ ((kr & 7) << 3))];
                sc[kt] = __builtin_amdgcn_mfma_f32_16x16x32_f16(kf, qf[ks], sc[kt], 0, 0, 0);
            }
        }
        __builtin_amdgcn_s_setprio(0);

        // p = exp2(sc*SC2 + mb); pack into P via b64 stores (static max).
        short* Pw = &QPs[wave * 1024];
        const int xsw = (lr & 7) << 3;
        #pragma unroll
        for (int kt = 0; kt < 4; ++kt) {
            const float p0 = exp2f(fmaf(sc[kt][0], SC2, mb[kt].x));
            const float p1 = exp2f(fmaf(sc[kt][1], SC2, mb[kt].y));
            const float p2 = exp2f(fmaf(sc[kt][2], SC2, mb[kt].z));
            const float p3 = exp2f(fmaf(sc[kt][3], SC2, mb[kt].w));
            const int cb = kt * 16 + lq * 4;
            uint2 pp;
            pp.x = pk2(p0, p1);
            pp.y = pk2(p2, p3);
            *(uint2*)&Pw[lr * 64 + (cb ^ xsw)] = pp;
        }

        // PV: A = P[q][k] (per-wave LDS), B = V[k][d] via Vt[d][k].
        // Extra ones-B MFMA accumulates row-sum l into ol (same layout as o).
        const short* Vts = VtsD[cur];
        half8 pf[2];
        #pragma unroll
        for (int ks = 0; ks < 2; ++ks)
            pf[ks] = *(const half8*)&Pw[lr * 64 + ((ks * 32 + lq * 8) ^ xsw)];
        __builtin_amdgcn_s_setprio(1);
        #pragma unroll
        for (int ks = 0; ks < 2; ++ks)
            ol = __builtin_amdgcn_mfma_f32_16x16x32_f16(pf[ks], ones8, ol, 0, 0, 0);
        #pragma unroll
        for (int dt = 0; dt < 4; ++dt) {
            const int dr = dt * 16 + lr;
            #pragma unroll
            for (int ks = 0; ks < 2; ++ks) {
                half8 vf = *(const half8*)&Vts[dr * 64 + ((ks * 32 + lq * 8) ^ ((dr & 7) << 3))];
                o[dt] = __builtin_amdgcn_mfma_f32_16x16x32_f16(pf[ks], vf, o[dt], 0, 0, 0);
            }
        }
        __builtin_amdgcn_s_setprio(0);

        // Single barrier per tile: drains next-tile staging (vmcnt) and
        // guards buf reuse + per-wave P region timing.
        __syncthreads();
        cur ^= 1;
    }

    // Epilogue: normalize by 1/l (register-local!), write fp16 (B,S,D)
    float linv[4];
    #pragma unroll
    for (int r = 0; r < 4; ++r) linv[r] = 1.0f / ol[r];
    const int srow = qt * 64 + wave * 16;
    #pragma unroll
    for (int dt = 0; dt < 4; ++dt)
        #pragma unroll
        for (int r = 0; r < 4; ++r)
            x[((size_t)b * SS + srow + lq * 4 + r) * DD + h * HD + dt * 16 + lr] =
                f2h(o[dt][r] * linv[r]);
}

extern "C" void kernel_launch(void* const* d_in, const int* in_sizes, int n_in,
                              void* d_out, int out_size, void* d_ws, size_t ws_size,
                              hipStream_t stream) {
    const float* query = (const float*)d_in[0];
    const float* key   = (const float*)d_in[1];
    const float* value = (const float*)d_in[2];
    const int*   mask  = (const int*)d_in[3];
    const float* Wq = (const float*)d_in[4];
    const float* bq = (const float*)d_in[5];
    const float* Wk = (const float*)d_in[6];
    const float* bk = (const float*)d_in[7];
    const float* Wv = (const float*)d_in[8];
    const float* bv = (const float*)d_in[9];
    const float* Wo = (const float*)d_in[10];
    const float* bo = (const float*)d_in[11];
    float* out = (float*)d_out;

    const size_t NACT = (size_t)MM * DD;   // 4M elements
    const size_t NW   = (size_t)DD * DD;   // 1M elements
    short* qry16 = (short*)d_ws;           // later reused as x16 (attn output)
    short* key16 = qry16 + NACT;
    short* val16 = key16 + NACT;
    short* wq16  = val16 + NACT;
    short* wk16  = wq16 + NW;
    short* wv16  = wk16 + NW;
    short* wo16  = wv16 + NW;
    short* q_ws  = wo16 + NW;
    short* k_ws  = q_ws + NACT;
    short* vt_ws = k_ws + NACT;
    float* mbias = (float*)(vt_ws + NACT);
    short* x16   = qry16;                  // reuse

    // 1. Convert activations + weights to fp16; build mask-bias array
    cvt_kernel<<<dim3(NACT / 4 / 256, 8), 256, 0, stream>>>(
        query, key, value, Wq, Wk, Wv, Wo, mask,
        qry16, key16, val16, wq16, wk16, wv16, wo16, mbias);

    // 2. Q/K/V projections (fused via grid.z)
    gemm_f16<<<dim3(MM / 128, DD / 128, 3), 256, 0, stream>>>(
        qry16, key16, val16, wq16, wk16, wv16, bq, bk, bv,
        q_ws, k_ws, vt_ws, 1, 1, 2);

    // 3. Attention (QBLK=64, 2-phase dbuf, MFMA row-sum)
    attn_mfma_kernel<<<dim3(SS / 64, HH, BB), 256, 0, stream>>>(
        q_ws, k_ws, vt_ws, mbias, x16);

    // 4. Output projection
    gemm_f16<<<dim3(MM / 128, DD / 128, 1), 256, 0, stream>>>(
        x16, x16, x16, wo16, wo16, wo16, bo, bo, bo,
        out, out, out, 0, 0, 0);
}

// Round 11
// 159.333 us; speedup vs baseline: 1.0730x; 1.0550x over previous
//
#include <hip/hip_runtime.h>
#include <hip/hip_bf16.h>
#include <hip/hip_fp16.h>

// Problem constants
#define BB 2
#define SS 2048
#define DD 1024
#define HH 16
#define HD 64
#define MM (BB * SS)   // 4096

typedef __attribute__((ext_vector_type(8))) _Float16 half8;
typedef __attribute__((ext_vector_type(4))) float f32x4;
typedef __attribute__((ext_vector_type(4))) short short4v;

static __device__ __forceinline__ short f2h(float f) {
    _Float16 h = (_Float16)f;
    return __builtin_bit_cast(short, h);
}

static __device__ __forceinline__ unsigned pk2(float a, float b) {
    auto h = __builtin_amdgcn_cvt_pkrtz(a, b);
    return __builtin_bit_cast(unsigned, h);
}

static __device__ __forceinline__ void gload16(const void* g, void* l) {
    __builtin_amdgcn_global_load_lds(
        (const __attribute__((address_space(1))) unsigned*)g,
        (__attribute__((address_space(3))) unsigned*)l, 16, 0, 0);
}

// ---------------------------------------------------------------------------
// fp32 -> fp16 conversion (activations+weights) + mask -> f32 bias array.
// ---------------------------------------------------------------------------
__global__ __launch_bounds__(256) void cvt_kernel(
    const float* __restrict__ q, const float* __restrict__ k, const float* __restrict__ v,
    const float* __restrict__ wq, const float* __restrict__ wk,
    const float* __restrict__ wv, const float* __restrict__ wo,
    const int* __restrict__ mask,
    short* __restrict__ q16, short* __restrict__ k16, short* __restrict__ v16,
    short* __restrict__ wq16, short* __restrict__ wk16,
    short* __restrict__ wv16, short* __restrict__ wo16,
    float* __restrict__ mbias)
{
    const int i = (blockIdx.x * 256 + threadIdx.x) * 4;
    if (blockIdx.y == 7) {
        if (i >= BB * SS) return;
        const int4 mi = *(const int4*)&mask[i];
        float4 f;
        f.x = (mi.x == 0) ? -1.0e9f : 0.0f;
        f.y = (mi.y == 0) ? -1.0e9f : 0.0f;
        f.z = (mi.z == 0) ? -1.0e9f : 0.0f;
        f.w = (mi.w == 0) ? -1.0e9f : 0.0f;
        *(float4*)&mbias[i] = f;
        return;
    }
    const float* src; short* dst; int n;
    switch (blockIdx.y) {
        case 0: src = q;  dst = q16;  n = MM * DD; break;
        case 1: src = k;  dst = k16;  n = MM * DD; break;
        case 2: src = v;  dst = v16;  n = MM * DD; break;
        case 3: src = wq; dst = wq16; n = DD * DD; break;
        case 4: src = wk; dst = wk16; n = DD * DD; break;
        case 5: src = wv; dst = wv16; n = DD * DD; break;
        default: src = wo; dst = wo16; n = DD * DD; break;
    }
    if (i >= n) return;
    const float4 f = *(const float4*)&src[i];
    short4v h;
    h.x = f2h(f.x); h.y = f2h(f.y); h.z = f2h(f.z); h.w = f2h(f.w);
    *(short4v*)&dst[i] = h;
}

// ---------------------------------------------------------------------------
// fp16 MFMA GEMM: C = A @ W^T + bias.  TM x 128 tile, BK=64, 4 waves,
// 16x16x32 MFMA, global_load_lds w=16 + XOR-swizzled ds_read_b128.
// TM=128: 2x2 waves of 64x64 (QKV, high per-block efficiency).
// TM=64:  1x4 waves of 64x32 (out-proj: doubles grid for occupancy).
// ---------------------------------------------------------------------------
template<int TM>
__global__ __launch_bounds__(256) void gemm_f16(
    const short* __restrict__ A0, const short* __restrict__ A1, const short* __restrict__ A2,
    const short* __restrict__ W0, const short* __restrict__ W1, const short* __restrict__ W2,
    const float* __restrict__ b0, const float* __restrict__ b1, const float* __restrict__ b2,
    void* __restrict__ C0, void* __restrict__ C1, void* __restrict__ C2,
    int mode0, int mode1, int mode2)
{
    constexpr int WAVES_N = (TM == 128) ? 2 : 4;
    constexpr int WN = 128 / WAVES_N;     // 64 or 32
    constexpr int NI = WN / 16;           // 4 or 2

    const int z = blockIdx.z;
    const short* A = (z == 0) ? A0 : (z == 1) ? A1 : A2;
    const short* W = (z == 0) ? W0 : (z == 1) ? W1 : W2;
    const float* bias = (z == 0) ? b0 : (z == 1) ? b1 : b2;
    void* C = (z == 0) ? C0 : (z == 1) ? C1 : C2;
    const int mode = (z == 0) ? mode0 : (z == 1) ? mode1 : mode2;

    __shared__ short Asw[TM * 64];
    __shared__ short Bsw[128 * 64];

    const int t = threadIdx.x;
    const int wave = t >> 6, lane = t & 63;
    const int lr = lane & 15, lq = lane >> 4;
    const int wr = wave / WAVES_N, wc = wave % WAVES_N;
    const int m0 = blockIdx.x * TM, n0 = blockIdx.y * 128;
    const int K = DD;

    f32x4 acc[4][NI] = {};

    for (int k0 = 0; k0 < K; k0 += 64) {
        #pragma unroll
        for (int c = 0; c < TM / 32; ++c) {
            const int b = c * 4096 + t * 16;
            const int row = b >> 7;
            const int coff = b & 127;
            const int scoff = coff ^ ((row & 7) << 4);
            gload16((const char*)A + ((size_t)(m0 + row) * K + k0) * 2 + scoff,
                    (char*)Asw + b);
        }
        #pragma unroll
        for (int c = 0; c < 4; ++c) {
            const int b = c * 4096 + t * 16;
            const int row = b >> 7;
            const int coff = b & 127;
            const int scoff = coff ^ ((row & 7) << 4);
            gload16((const char*)W + ((size_t)(n0 + row) * K + k0) * 2 + scoff,
                    (char*)Bsw + b);
        }
        __syncthreads();

        half8 af[4][2], bf[NI][2];
        #pragma unroll
        for (int mi = 0; mi < 4; ++mi) {
            const int row = wr * 64 + mi * 16 + lr;
            #pragma unroll
            for (int ks = 0; ks < 2; ++ks) {
                const int col = (ks * 32 + lq * 8) ^ ((row & 7) << 3);
                af[mi][ks] = *(const half8*)&Asw[row * 64 + col];
            }
        }
        #pragma unroll
        for (int ni = 0; ni < NI; ++ni) {
            const int row = wc * WN + ni * 16 + lr;
            #pragma unroll
            for (int ks = 0; ks < 2; ++ks) {
                const int col = (ks * 32 + lq * 8) ^ ((row & 7) << 3);
                bf[ni][ks] = *(const half8*)&Bsw[row * 64 + col];
            }
        }
        #pragma unroll
        for (int ks = 0; ks < 2; ++ks)
            #pragma unroll
            for (int mi = 0; mi < 4; ++mi)
                #pragma unroll
                for (int ni = 0; ni < NI; ++ni)
                    acc[mi][ni] = __builtin_amdgcn_mfma_f32_16x16x32_f16(
                        af[mi][ks], bf[ni][ks], acc[mi][ni], 0, 0, 0);
        __syncthreads();
    }

    #pragma unroll
    for (int mi = 0; mi < 4; ++mi) {
        #pragma unroll
        for (int r = 0; r < 4; ++r) {
            const int m = m0 + wr * 64 + mi * 16 + lq * 4 + r;
            const int bidx = m >> 11;
            const int s = m & (SS - 1);
            #pragma unroll
            for (int ni = 0; ni < NI; ++ni) {
                const int n = n0 + wc * WN + ni * 16 + lr;
                const float val = acc[mi][ni][r] + bias[n];
                if (mode == 0) {
                    ((float*)C)[(size_t)m * DD + n] = val;
                } else {
                    const int h = n >> 6, d = n & (HD - 1);
                    if (mode == 1)
                        ((short*)C)[(((size_t)bidx * HH + h) * SS + s) * HD + d] = f2h(val);
                    else
                        ((short*)C)[(((size_t)bidx * HH + h) * HD + d) * SS + s] = f2h(val);
                }
            }
        }
    }
}

// ---------------------------------------------------------------------------
// MFMA flash attention (fp16), swapped-QK^T + static-max softmax +
// 2-phase double-buffered K/V, STATICALLY 2x-UNROLLED over the buffers so
// all LDS addresses are compile-time (fold into ds offset immediates) +
// MFMA row-sum (l = P @ ones) + b64 P-stores.
// LDS = 8K (Q/P overlay) + 16K (K dbuf) + 16K (V dbuf) = 40960 B.
// ---------------------------------------------------------------------------
static __device__ __forceinline__ void attn_tile_body(
    const short* __restrict__ Ks, const short* __restrict__ Vts,
    char* KsN, char* VtsN,
    const char* kb, const char* vb,
    int kv_stage, bool do_stage,
    const float* mrow, int kv0,
    const half8 qf[2], short* Pw,
    int t, int lr, int lq,
    f32x4 o[4], f32x4& ol, half8 ones8)
{
    const float SC2 = 0.18033688011112042f;   // 0.125 * log2(e)

    // Issue next tile's staging loads (latency hidden under compute)
    if (do_stage) {
        #pragma unroll
        for (int c = 0; c < 2; ++c) {
            const int off = c * 4096 + t * 16;
            const int row = off >> 7, coff = off & 127;
            const int sw = coff ^ ((row & 7) << 4);
            gload16(kb + (size_t)(kv_stage + row) * 128 + sw, KsN + off);
            gload16(vb + (size_t)row * (SS * 2) + kv_stage * 2 + sw, VtsN + off);
        }
    }

    // Mask bias for this tile (global, L1/L2 broadcast)
    float4 mb[4];
    #pragma unroll
    for (int kt = 0; kt < 4; ++kt)
        mb[kt] = *(const float4*)&mrow[kv0 + kt * 16 + lq * 4];

    // Swapped QK^T: sc[kt] row = k (lq*4+r), col = q (lr)
    f32x4 sc[4] = {};
    __builtin_amdgcn_s_setprio(1);
    #pragma unroll
    for (int kt = 0; kt < 4; ++kt) {
        const int kr = kt * 16 + lr;
        #pragma unroll
        for (int ks = 0; ks < 2; ++ks) {
            half8 kf = *(const half8*)&Ks[kr * 64 + ((ks * 32 + lq * 8) ^ ((kr & 7) << 3))];
            sc[kt] = __builtin_amdgcn_mfma_f32_16x16x32_f16(kf, qf[ks], sc[kt], 0, 0, 0);
        }
    }
    __builtin_amdgcn_s_setprio(0);

    // p = exp2(sc*SC2 + mb); pack into P via b64 stores (static max).
    const int xsw = (lr & 7) << 3;
    #pragma unroll
    for (int kt = 0; kt < 4; ++kt) {
        const float p0 = exp2f(fmaf(sc[kt][0], SC2, mb[kt].x));
        const float p1 = exp2f(fmaf(sc[kt][1], SC2, mb[kt].y));
        const float p2 = exp2f(fmaf(sc[kt][2], SC2, mb[kt].z));
        const float p3 = exp2f(fmaf(sc[kt][3], SC2, mb[kt].w));
        const int cb = kt * 16 + lq * 4;
        uint2 pp;
        pp.x = pk2(p0, p1);
        pp.y = pk2(p2, p3);
        *(uint2*)&Pw[lr * 64 + (cb ^ xsw)] = pp;
    }

    // PV: A = P[q][k] (per-wave LDS), B = V[k][d] via Vt[d][k].
    // Extra ones-B MFMA accumulates row-sum l into ol (same layout as o).
    half8 pf[2];
    #pragma unroll
    for (int ks = 0; ks < 2; ++ks)
        pf[ks] = *(const half8*)&Pw[lr * 64 + ((ks * 32 + lq * 8) ^ xsw)];
    __builtin_amdgcn_s_setprio(1);
    #pragma unroll
    for (int ks = 0; ks < 2; ++ks)
        ol = __builtin_amdgcn_mfma_f32_16x16x32_f16(pf[ks], ones8, ol, 0, 0, 0);
    #pragma unroll
    for (int dt = 0; dt < 4; ++dt) {
        const int dr = dt * 16 + lr;
        #pragma unroll
        for (int ks = 0; ks < 2; ++ks) {
            half8 vf = *(const half8*)&Vts[dr * 64 + ((ks * 32 + lq * 8) ^ ((dr & 7) << 3))];
            o[dt] = __builtin_amdgcn_mfma_f32_16x16x32_f16(pf[ks], vf, o[dt], 0, 0, 0);
        }
    }
    __builtin_amdgcn_s_setprio(0);

    // Single barrier per tile: drains staging (vmcnt) + guards buf reuse.
    __syncthreads();
}

__global__ __launch_bounds__(256) void attn_mfma_kernel(
    const short* __restrict__ q,
    const short* __restrict__ k,
    const short* __restrict__ vt,
    const float* __restrict__ mbias,
    short* __restrict__ x)
{
    const int qt = blockIdx.x;   // 0..31
    const int h  = blockIdx.y;   // 0..15
    const int b  = blockIdx.z;   // 0..1
    const int t = threadIdx.x;
    const int wave = t >> 6, lane = t & 63;
    const int lr = lane & 15;
    const int lq = lane >> 4;

    __shared__ short QPs[64 * 64];        // Q tile, then per-wave P tiles
    __shared__ short KsD[2][64 * 64];
    __shared__ short VtsD[2][64 * 64];

    const size_t base  = ((size_t)(b * HH + h)) * SS * HD;
    const size_t basev = ((size_t)(b * HH + h)) * HD * SS;
    const char* kb = (const char*)(k + base);
    const char* vb = (const char*)(vt + basev);

    // Stage Q tile (64 x 64) + K/V tile 0 into buffer 0
    {
        const char* qb = (const char*)(q + base + (size_t)qt * 64 * HD);
        #pragma unroll
        for (int c = 0; c < 2; ++c) {
            const int off = c * 4096 + t * 16;
            const int row = off >> 7, coff = off & 127;
            const int sw = coff ^ ((row & 7) << 4);
            gload16(qb + row * 128 + sw, (char*)QPs + off);
            gload16(kb + (size_t)row * 128 + sw, (char*)KsD[0] + off);
            gload16(vb + (size_t)row * (SS * 2) + sw, (char*)VtsD[0] + off);
        }
    }
    __syncthreads();

    half8 qf[2];
    #pragma unroll
    for (int ks = 0; ks < 2; ++ks) {
        const int r = wave * 16 + lr;
        qf[ks] = *(const half8*)&QPs[r * 64 + ((ks * 32 + lq * 8) ^ ((r & 7) << 3))];
    }
    __syncthreads();   // all waves done reading Q before P overwrites it

    f32x4 o[4] = {};
    f32x4 ol = {};                       // MFMA-accumulated row sums (l)
    const float* mrow = &mbias[b * SS];
    short* Pw = &QPs[wave * 1024];

    const half8 ones8 = {1.0f16, 1.0f16, 1.0f16, 1.0f16,
                         1.0f16, 1.0f16, 1.0f16, 1.0f16};

    // Statically 2x-unrolled double-buffer loop (compile-time LDS bases).
    for (int kv0 = 0; kv0 < SS; kv0 += 128) {
        attn_tile_body(KsD[0], VtsD[0], (char*)KsD[1], (char*)VtsD[1],
                       kb, vb, kv0 + 64, true,
                       mrow, kv0, qf, Pw, t, lr, lq, o, ol, ones8);
        attn_tile_body(KsD[1], VtsD[1], (char*)KsD[0], (char*)VtsD[0],
                       kb, vb, kv0 + 128, (kv0 + 128) < SS,
                       mrow, kv0 + 64, qf, Pw, t, lr, lq, o, ol, ones8);
    }

    // Epilogue: normalize by 1/l (register-local), write fp16 (B,S,D)
    float linv[4];
    #pragma unroll
    for (int r = 0; r < 4; ++r) linv[r] = 1.0f / ol[r];
    const int srow = qt * 64 + wave * 16;
    #pragma unroll
    for (int dt = 0; dt < 4; ++dt)
        #pragma unroll
        for (int r = 0; r < 4; ++r)
            x[((size_t)b * SS + srow + lq * 4 + r) * DD + h * HD + dt * 16 + lr] =
                f2h(o[dt][r] * linv[r]);
}

extern "C" void kernel_launch(void* const* d_in, const int* in_sizes, int n_in,
                              void* d_out, int out_size, void* d_ws, size_t ws_size,
                              hipStream_t stream) {
    const float* query = (const float*)d_in[0];
    const float* key   = (const float*)d_in[1];
    const float* value = (const float*)d_in[2];
    const int*   mask  = (const int*)d_in[3];
    const float* Wq = (const float*)d_in[4];
    const float* bq = (const float*)d_in[5];
    const float* Wk = (const float*)d_in[6];
    const float* bk = (const float*)d_in[7];
    const float* Wv = (const float*)d_in[8];
    const float* bv = (const float*)d_in[9];
    const float* Wo = (const float*)d_in[10];
    const float* bo = (const float*)d_in[11];
    float* out = (float*)d_out;

    const size_t NACT = (size_t)MM * DD;   // 4M elements
    const size_t NW   = (size_t)DD * DD;   // 1M elements
    short* qry16 = (short*)d_ws;           // later reused as x16 (attn output)
    short* key16 = qry16 + NACT;
    short* val16 = key16 + NACT;
    short* wq16  = val16 + NACT;
    short* wk16  = wq16 + NW;
    short* wv16  = wk16 + NW;
    short* wo16  = wv16 + NW;
    short* q_ws  = wo16 + NW;
    short* k_ws  = q_ws + NACT;
    short* vt_ws = k_ws + NACT;
    float* mbias = (float*)(vt_ws + NACT);
    short* x16   = qry16;                  // reuse

    // 1. Convert activations + weights to fp16; build mask-bias array
    cvt_kernel<<<dim3(NACT / 4 / 256, 8), 256, 0, stream>>>(
        query, key, value, Wq, Wk, Wv, Wo, mask,
        qry16, key16, val16, wq16, wk16, wv16, wo16, mbias);

    // 2. Q/K/V projections (fused via grid.z, 128x128 tiles, 3 blocks/CU)
    gemm_f16<128><<<dim3(MM / 128, DD / 128, 3), 256, 0, stream>>>(
        qry16, key16, val16, wq16, wk16, wv16, bq, bk, bv,
        q_ws, k_ws, vt_ws, 1, 1, 2);

    // 3. Attention (QBLK=64, 2-phase dbuf, statically unrolled)
    attn_mfma_kernel<<<dim3(SS / 64, HH, BB), 256, 0, stream>>>(
        q_ws, k_ws, vt_ws, mbias, x16);

    // 4. Output projection (64x128 tiles -> 512 blocks for occupancy)
    gemm_f16<64><<<dim3(MM / 64, DD / 128, 1), 256, 0, stream>>>(
        x16, x16, x16, wo16, wo16, wo16, bo, bo, bo,
        out, out, out, 0, 0, 0);
}